// Round 1
// baseline (162.896 us; speedup 1.0000x reference)
//
#include <hip/hip_runtime.h>

typedef __attribute__((ext_vector_type(4))) float f32x4;
typedef __attribute__((ext_vector_type(8))) short s16x8;
typedef __attribute__((ext_vector_type(4))) int   i32x4;

#define C_DIM 256
#define H_DIM 128
#define W_DIM 512
#define HW    (H_DIM * W_DIM)      /* 65536  */
#define CHW   (C_DIM * HW)         /* 16777216 */

__device__ __forceinline__ unsigned short f2bf(float f) {
    unsigned u = __builtin_bit_cast(unsigned, f);
    u = (u + 0x7FFFu + ((u >> 16) & 1u)) >> 16;   // round-to-nearest-even
    return (unsigned short)u;
}

// One WG per (b, h, 64-row w1 block). 16 waves, wave grid 2(M) x 8(N).
// vol[w1][w2] = dot_c(img1[b,c,h,w1], img2[b,c,h,w2]) / 16, full N=512 in acc.
__global__ __launch_bounds__(1024, 4) void costvol_kernel(
    const float* __restrict__ img1, const float* __restrict__ img2,
    const float* __restrict__ intri1,
    const float* __restrict__ extri1, const float* __restrict__ extri2,
    float* __restrict__ out)
{
    __shared__ __align__(16) unsigned char smem[65536];
    unsigned short* Alds = (unsigned short*)smem;        // [64][256] bf16, [m][k], 16B-block XOR swizzle
    unsigned*       Blds = (unsigned*)(smem + 32768);    // [16][512] dwords: k-pair interleaved, swizzled

    const int t = threadIdx.x;
    const int d = blockIdx.x;
    // XCD swizzle: the 8 blocks sharing (b,h) get dispatch ids stride-8 apart -> same XCD, concurrent
    const int win = d >> 6, pos = d & 63;
    const int bh    = win * 8 + (pos & 7);
    const int w1blk = pos >> 3;
    const int b = bh >> 7, h = bh & 127;
    const int w1base = w1blk * 64;

    const float* i1 = img1 + (size_t)b * CHW + (size_t)h * W_DIM;
    const float* i2 = img2 + (size_t)b * CHW + (size_t)h * W_DIM;

    // ---- stage A once: rows w1base..+63, all K=256, transposed to [m][k] bf16
    {
        const int c    = t >> 2;                 // 0..255
        const int wseg = (t & 3) << 4;           // 0,16,32,48
        const float* src = i1 + (size_t)c * HW + (size_t)(w1base + wseg);
        #pragma unroll
        for (int i0 = 0; i0 < 16; i0 += 4) {
            f32x4 v = *(const f32x4*)(src + i0);
            #pragma unroll
            for (int j = 0; j < 4; ++j) {
                const int w = wseg + i0 + j;
                Alds[w * 256 + ((((c >> 3) ^ (w & 15)) << 3) | (c & 7))] = f2bf(v[j]);
            }
        }
    }

    const int wv = t >> 6, lane = t & 63;
    const int wm = wv >> 3, wn = wv & 7;         // wave tile: rows [32*wm,+32), cols [64*wn,+64)
    const int lrow = lane & 15, hq = lane >> 4;

    f32x4 acc[2][4] = {};

    const int kpS   = t >> 6;                    // staging: pair row 0..15
    const int w0S   = (t & 63) << 3;             // staging: dword col base
    const int w0Ssw = w0S ^ ((kpS >> 2) << 3);   // bank swizzle (matches read side)

    for (int kc = 0; kc < 8; ++kc) {
        const int c0 = kc << 5;                  // K chunk of 32 channels
        // ---- stage B chunk: channels c0..c0+31 pair-interleaved: dword = (bf16(c even) | bf16(c odd)<<16)
        {
            const float* r0 = i2 + (size_t)(c0 + 2 * kpS) * HW + w0S;
            const float* r1 = r0 + HW;
            f32x4 a0 = *(const f32x4*)(r0);
            f32x4 a1 = *(const f32x4*)(r0 + 4);
            f32x4 b0 = *(const f32x4*)(r1);
            f32x4 b1 = *(const f32x4*)(r1 + 4);
            i32x4 d0, d1;
            #pragma unroll
            for (int j = 0; j < 4; ++j) {
                d0[j] = (int)((unsigned)f2bf(a0[j]) | ((unsigned)f2bf(b0[j]) << 16));
                d1[j] = (int)((unsigned)f2bf(a1[j]) | ((unsigned)f2bf(b1[j]) << 16));
            }
            *(i32x4*)&Blds[kpS * 512 + w0Ssw]     = d0;
            *(i32x4*)&Blds[kpS * 512 + (w0Ssw + 4)] = d1;
        }
        __syncthreads();

        // ---- fragments + MFMA. A frag: lane row=l&15, k = c0 + 8*(l>>4) + j (contiguous 8)
        s16x8 afr[2];
        #pragma unroll
        for (int rt = 0; rt < 2; ++rt) {
            const int row = 32 * wm + 16 * rt + lrow;
            const int kb  = (kc << 2) + hq;
            afr[rt] = *(const s16x8*)&Alds[row * 256 + ((kb ^ (row & 15)) << 3)];
        }
        #pragma unroll
        for (int ct = 0; ct < 4; ++ct) {
            const int n   = 64 * wn + 16 * ct + lrow;
            const int nsw = n ^ (hq << 3);
            i32x4 bw;
            #pragma unroll
            for (int p = 0; p < 4; ++p)
                bw[p] = (int)Blds[(4 * hq + p) * 512 + nsw];
            const s16x8 bfr = __builtin_bit_cast(s16x8, bw);
            acc[0][ct] = __builtin_amdgcn_mfma_f32_16x16x32_bf16(afr[0], bfr, acc[0][ct], 0, 0, 0);
            acc[1][ct] = __builtin_amdgcn_mfma_f32_16x16x32_bf16(afr[1], bfr, acc[1][ct], 0, 0, 0);
        }
        __syncthreads();
    }

    // ---- epilogue: per-row Se = sum(e), Sei = sum(e*col | col<=w1), Me = max(e | col<=w1)
    // D layout (m89): col = lane&15, row = 4*(lane>>4) + reg
    float (*red)[64][3] = (float(*)[64][3])smem;   // aliases Alds (dead after last barrier)
    #pragma unroll
    for (int rt = 0; rt < 2; ++rt) {
        #pragma unroll
        for (int r = 0; r < 4; ++r) {
            const int row = 32 * wm + 16 * rt + 4 * hq + r;
            const int w1g = w1base + row;
            float Se = 0.f, Sei = 0.f, Me = 0.f;
            #pragma unroll
            for (int ct = 0; ct < 4; ++ct) {
                const int col = 64 * wn + 16 * ct + lrow;
                const float e = __expf(acc[rt][ct][r] * 0.0625f);   // fold 1/sqrt(256)
                Se += e;
                if (col <= w1g) { Sei += e * (float)col; Me = fmaxf(Me, e); }
            }
            #pragma unroll
            for (int m = 1; m < 16; m <<= 1) {
                Se  += __shfl_xor(Se,  m, 64);
                Sei += __shfl_xor(Sei, m, 64);
                Me   = fmaxf(Me, __shfl_xor(Me, m, 64));
            }
            if (lrow == 0) {
                red[wn][row][0] = Se;
                red[wn][row][1] = Sei;
                red[wn][row][2] = Me;
            }
        }
    }
    __syncthreads();

    if (t < 64) {
        const int row = t;
        float Se = 0.f, Sei = 0.f, Me = 0.f;
        #pragma unroll
        for (int q = 0; q < 8; ++q) {
            Se += red[q][row][0];
            Sei += red[q][row][1];
            Me  = fmaxf(Me, red[q][row][2]);
        }
        const int w1g = w1base + row;
        const float corresp = Sei / Se;            // soft-argmax (masked numerator, full denominator)
        const float conf    = Me / Se;             // max of post-softmax masked prob
        float disp = fabsf(corresp - (float)w1g) * (1.0f / 512.0f);
        disp = fmaxf(disp, 0.1f);
        const float fx = intri1[b * 9];
        const float dx = extri1[b * 16 + 3]  - extri2[b * 16 + 3];
        const float dy = extri1[b * 16 + 7]  - extri2[b * 16 + 7];
        const float dz = extri1[b * 16 + 11] - extri2[b * 16 + 11];
        const float bl = sqrtf(dx * dx + dy * dy + dz * dz);
        const float depth = fx * bl / disp;
        const int oidx = b * HW + h * W_DIM + w1g;
        out[oidx]                 = depth;
        out[2 * HW + oidx]        = conf;          // confidence block starts at B*H*W = 131072
    }
}

extern "C" void kernel_launch(void* const* d_in, const int* in_sizes, int n_in,
                              void* d_out, int out_size, void* d_ws, size_t ws_size,
                              hipStream_t stream) {
    const float* img1   = (const float*)d_in[0];
    const float* img2   = (const float*)d_in[1];
    const float* intri1 = (const float*)d_in[2];
    const float* extri1 = (const float*)d_in[4];
    const float* extri2 = (const float*)d_in[5];
    costvol_kernel<<<dim3(2048), dim3(1024), 0, stream>>>(
        img1, img2, intri1, extri1, extri2, (float*)d_out);
}

// Round 2
// 127.744 us; speedup vs baseline: 1.2752x; 1.2752x over previous
//
#include <hip/hip_runtime.h>

typedef __attribute__((ext_vector_type(4))) float f32x4;
typedef __attribute__((ext_vector_type(8))) short s16x8;

#define C_DIM 256
#define H_DIM 128
#define W_DIM 512
#define HW    (H_DIM * W_DIM)      /* 65536  */
#define CHW   (C_DIM * HW)         /* 16777216 */

__device__ __forceinline__ unsigned short f2bf(float f) {
    unsigned u = __builtin_bit_cast(unsigned, f);
    u = (u + 0x7FFFu + ((u >> 16) & 1u)) >> 16;   // round-to-nearest-even
    return (unsigned short)u;
}

// One WG per (b, h, 64-row w1 block). 512 threads = 8 waves, wave grid 1(M) x 8(N).
// Each wave: M=64 rows x N=64 cols. A staged once in LDS (bf16, swizzled);
// B fragments loaded DIRECTLY global->reg (no LDS, no per-chunk barriers).
__global__ __launch_bounds__(512, 4) void costvol_kernel(
    const float* __restrict__ img1, const float* __restrict__ img2,
    const float* __restrict__ intri1,
    const float* __restrict__ extri1, const float* __restrict__ extri2,
    float* __restrict__ out)
{
    __shared__ __align__(16) unsigned char smem[32768];
    unsigned short* Alds = (unsigned short*)smem;  // [64][256] bf16, [m][k], 16B-block XOR swizzle

    const int t = threadIdx.x;
    const int d = blockIdx.x;
    // XCD swizzle: the 8 blocks sharing (b,h) get dispatch ids stride-8 apart -> same XCD
    const int win = d >> 6, pos = d & 63;
    const int bh    = win * 8 + (pos & 7);
    const int w1blk = pos >> 3;
    const int b = bh >> 7, h = bh & 127;
    const int w1base = w1blk * 64;

    const float* i1 = img1 + (size_t)b * CHW + (size_t)h * W_DIM;
    const float* i2 = img2 + (size_t)b * CHW + (size_t)h * W_DIM;

    // ---- stage A once: rows w1base..+63, all K=256, transposed to [m][k] bf16
    {
        const int c    = t >> 1;                 // 0..255
        const int wseg = (t & 1) << 5;           // 0 or 32
        const float* src = i1 + (size_t)c * HW + (size_t)(w1base + wseg);
        #pragma unroll
        for (int i0 = 0; i0 < 32; i0 += 4) {
            f32x4 v = *(const f32x4*)(src + i0);
            #pragma unroll
            for (int j = 0; j < 4; ++j) {
                const int w = wseg + i0 + j;
                Alds[w * 256 + ((((c >> 3) ^ (w & 15)) << 3) | (c & 7))] = f2bf(v[j]);
            }
        }
    }
    __syncthreads();

    const int wn = t >> 6, lane = t & 63;
    const int lrow = lane & 15, hq = lane >> 4;

    // B column base pointers: lane covers column n at k-rows 8*hq + j
    const float* pb[4];
    #pragma unroll
    for (int ct = 0; ct < 4; ++ct)
        pb[ct] = i2 + (size_t)(8 * hq) * HW + (64 * wn + 16 * ct + lrow);

    f32x4 acc[4][4] = {};

    for (int kc = 0; kc < 8; ++kc) {
        // A fragments: lane row = lrow, k = 32*kc + 8*hq + j (contiguous 8)
        s16x8 afr[4];
        #pragma unroll
        for (int rt = 0; rt < 4; ++rt) {
            const int row = 16 * rt + lrow;
            const int kb  = (kc << 2) + hq;
            afr[rt] = *(const s16x8*)&Alds[row * 256 + ((kb ^ (row & 15)) << 3)];
        }
        #pragma unroll
        for (int ct = 0; ct < 4; ++ct) {
            const float* p = pb[ct] + (size_t)(32 * kc) * HW;
            float f[8];
            #pragma unroll
            for (int j = 0; j < 8; ++j) f[j] = p[(size_t)j * HW];
            unsigned dw[4];
            #pragma unroll
            for (int q = 0; q < 4; ++q)
                dw[q] = (unsigned)f2bf(f[2 * q]) | ((unsigned)f2bf(f[2 * q + 1]) << 16);
            s16x8 bfr;
            #pragma unroll
            for (int q = 0; q < 4; ++q) {
                bfr[2 * q]     = (short)(dw[q] & 0xFFFFu);
                bfr[2 * q + 1] = (short)(dw[q] >> 16);
            }
            #pragma unroll
            for (int rt = 0; rt < 4; ++rt)
                acc[rt][ct] = __builtin_amdgcn_mfma_f32_16x16x32_bf16(afr[rt], bfr, acc[rt][ct], 0, 0, 0);
        }
    }

    __syncthreads();   // A LDS dead; reuse for cross-wave reduction

    // ---- epilogue: per-row Se = sum(e), Sei = sum(e*col | col<=w1), Me = max(e | col<=w1)
    // D layout (m89): col = lane&15, row = 4*(lane>>4) + reg
    float (*red)[64][3] = (float(*)[64][3])smem;
    #pragma unroll
    for (int rt = 0; rt < 4; ++rt) {
        #pragma unroll
        for (int r = 0; r < 4; ++r) {
            const int row = 16 * rt + 4 * hq + r;
            const int w1g = w1base + row;
            float Se = 0.f, Sei = 0.f, Me = 0.f;
            #pragma unroll
            for (int ct = 0; ct < 4; ++ct) {
                const int col = 64 * wn + 16 * ct + lrow;
                const float e = __expf(acc[rt][ct][r] * 0.0625f);   // fold 1/sqrt(256)
                Se += e;
                if (col <= w1g) { Sei += e * (float)col; Me = fmaxf(Me, e); }
            }
            #pragma unroll
            for (int m = 1; m < 16; m <<= 1) {
                Se  += __shfl_xor(Se,  m, 64);
                Sei += __shfl_xor(Sei, m, 64);
                Me   = fmaxf(Me, __shfl_xor(Me, m, 64));
            }
            if (lrow == 0) {
                red[wn][row][0] = Se;
                red[wn][row][1] = Sei;
                red[wn][row][2] = Me;
            }
        }
    }
    __syncthreads();

    if (t < 64) {
        const int row = t;
        float Se = 0.f, Sei = 0.f, Me = 0.f;
        #pragma unroll
        for (int q = 0; q < 8; ++q) {
            Se  += red[q][row][0];
            Sei += red[q][row][1];
            Me   = fmaxf(Me, red[q][row][2]);
        }
        const int w1g = w1base + row;
        const float corresp = Sei / Se;            // soft-argmax (masked numerator, full denominator)
        const float conf    = Me / Se;             // max of post-softmax masked prob
        float disp = fabsf(corresp - (float)w1g) * (1.0f / 512.0f);
        disp = fmaxf(disp, 0.1f);
        const float fx = intri1[b * 9];
        const float dx = extri1[b * 16 + 3]  - extri2[b * 16 + 3];
        const float dy = extri1[b * 16 + 7]  - extri2[b * 16 + 7];
        const float dz = extri1[b * 16 + 11] - extri2[b * 16 + 11];
        const float bl = sqrtf(dx * dx + dy * dy + dz * dz);
        const float depth = fx * bl / disp;
        const int oidx = b * HW + h * W_DIM + w1g;
        out[oidx]          = depth;
        out[2 * HW + oidx] = conf;                 // confidence block starts at B*H*W = 131072
    }
}

extern "C" void kernel_launch(void* const* d_in, const int* in_sizes, int n_in,
                              void* d_out, int out_size, void* d_ws, size_t ws_size,
                              hipStream_t stream) {
    const float* img1   = (const float*)d_in[0];
    const float* img2   = (const float*)d_in[1];
    const float* intri1 = (const float*)d_in[2];
    const float* extri1 = (const float*)d_in[4];
    const float* extri2 = (const float*)d_in[5];
    costvol_kernel<<<dim3(2048), dim3(512), 0, stream>>>(
        img1, img2, intri1, extri1, extri2, (float*)d_out);
}